// Round 13
// baseline (143.746 us; speedup 1.0000x reference)
//
#include <hip/hip_runtime.h>
#include <math.h>

// CircleLoss fused, R13: one block per CU, A panel in registers (for real).
// R8-R12 post-mortem: wall 65-80us across five structures with all pipes
// idle (Mfma 8%, VALU 16-18%) and time-avg occupancy 15% vs 50% instantaneous
// -> the wall is TAIL/STRAGGLER time, not stall-per-instruction. At 2 blocks/
// CU the wall = sum of two blocks' tails and the 128-VGPR cap poisoned every
// register plan (R7 spill, R11 remat, R12 LDS detour). Fix: grid 256 = 1
// block/CU, launch_bounds(512,1) -> VGPR cap 256: A-frags live in registers
// (~170 VGPR, no remat/spill), B direct global->reg (L2-hot), no barriers,
// no LDS staging at all; colbuf (74KB) free at 1 block/CU; block-end atomic
// bursts halve.
// Dense: all off-diag sims negative, 7-inst epilogue (R10-proven); sparse
// positive pass fused in tail, 2 classes/block (R11-proven math, orientation
// matched). classbuild fused into normalize. 3 dispatches.
// sim = xn @ xn^T, 2-term split-bf16: sim ~= (hiA+loA).hiB (drop A.loB ~2e-4).
// Pairing: panel p + panel 63-p = 65 tiles, 8 blocks/pair, 8-9 tiles/block.
// loss = mean(log1p(sumP*sumN)); fence-free counter finalize (R4-proven).

#define NR    8192
#define DIMK  128
#define NT    64
#define NBLKS 256
#define CCAP  64    // class-member capacity (Poisson(16) > 64: P ~ 1e-20)

typedef __attribute__((ext_vector_type(8))) short short8;
typedef __attribute__((ext_vector_type(4))) float f32x4;

__device__ __forceinline__ unsigned short bf16_rne(float f) {
  uint32_t u = __float_as_uint(f);
  u += 0x7FFFu + ((u >> 16) & 1u);
  return (unsigned short)(u >> 16);
}
__device__ __forceinline__ float b2f(unsigned short h) {
  return __uint_as_float((uint32_t)h << 16);
}

// ws: xhi bf16[NR*DIMK] (2MB) | xlo (2MB) | gP f32[NR] | gN f32[NR] |
//     counter int | pad | cnt int[512] | members int[512*CCAP]

__global__ __launch_bounds__(256) void normalize_split_kernel(
    const float* __restrict__ x, const int* __restrict__ tgt,
    unsigned short* __restrict__ xhi, unsigned short* __restrict__ xlo,
    float* __restrict__ gP, float* __restrict__ gN,
    int* __restrict__ counter, int* __restrict__ cnt, int* __restrict__ mem) {
  if (blockIdx.x < 32)      gP[blockIdx.x * 256 + threadIdx.x] = 0.f;
  else if (blockIdx.x < 64) gN[(blockIdx.x - 32) * 256 + threadIdx.x] = 0.f;
  if (blockIdx.x == 64 && threadIdx.x == 0) *counter = 0;

  const int wave = threadIdx.x >> 6;
  const int lane = threadIdx.x & 63;
  const int row  = blockIdx.x * 4 + wave;
  const float2 v = ((const float2*)(x + (size_t)row * DIMK))[lane];
  float ss = v.x * v.x + v.y * v.y;
  #pragma unroll
  for (int s = 1; s < 64; s <<= 1) ss += __shfl_xor(ss, s);
  const float r = rsqrtf(ss);
  const float a = v.x * r, b = v.y * r;
  const unsigned short ha = bf16_rne(a), hb = bf16_rne(b);
  const float haf = __uint_as_float((uint32_t)ha << 16);
  const float hbf = __uint_as_float((uint32_t)hb << 16);
  ushort2 hi, lo;
  hi.x = ha; hi.y = hb;
  lo.x = bf16_rne(a - haf); lo.y = bf16_rne(b - hbf);
  ((ushort2*)xhi)[(size_t)row * 64 + lane] = hi;
  ((ushort2*)xlo)[(size_t)row * 64 + lane] = lo;

  // fused classbuild (cnt pre-zeroed by hipMemsetAsync)
  if (lane == 0) {
    const int c = tgt[row];
    const int idx = atomicAdd(&cnt[c], 1);
    if (idx < CCAP) mem[c * CCAP + idx] = row;
  }
}

__global__ __launch_bounds__(512, 1) void simloss_kernel(
    const unsigned short* __restrict__ xhi, const unsigned short* __restrict__ xlo,
    const int* __restrict__ cnt, const int* __restrict__ mem,
    float* __restrict__ gP, float* __restrict__ gN,
    int* __restrict__ counter, float* __restrict__ out) {
  __shared__ float colbuf[9][4][128];   // 18K floats = 72KB (1 block/CU: fine)
  __shared__ float red[512];
  __shared__ int islast;

  const int tid  = threadIdx.x;
  const int wave = tid >> 6, lane = tid & 63;
  const int wy = wave & 3, wx = wave >> 2;   // frag grid: 4 row-waves x 2 col-waves
  const int q = lane >> 4, mcol = lane & 15;

  // pairing: 65 tiles/pair, 8 blocks/pair (8-9 tiles), grid 256
  const int p  = blockIdx.x >> 3;
  const int b  = blockIdx.x & 7;
  const int n1 = NT - p;
  const int p2 = NT - 1 - p;
  const int t0 = (b * (NT + 1)) >> 3;
  const int t1 = ((b + 1) * (NT + 1)) >> 3;
  const int ntile = t1 - t0;

  short8 Ah[2][4], Al[2][4];
  auto loadA = [&](int bi) {
    #pragma unroll
    for (int fr = 0; fr < 2; ++fr) {
      const int r = bi * 128 + wy * 32 + fr * 16 + mcol;
      const unsigned short* gh = xhi + (size_t)r * DIMK + q * 8;
      const unsigned short* gl = xlo + (size_t)r * DIMK + q * 8;
      #pragma unroll
      for (int ks = 0; ks < 4; ++ks) {
        Ah[fr][ks] = *(const short8*)(gh + ks * 32);
        Al[fr][ks] = *(const short8*)(gl + ks * 32);
      }
    }
  };

  float rowNa[2][4] = {{0.f}}, rowNb[2][4] = {{0.f}};  // per-panel row sums

  int cur_bi = (t0 < n1) ? p : p2;
  loadA(cur_bi);

  for (int tl = 0; tl < ntile; ++tl) {
    const int ix = t0 + tl;
    const bool in1 = (ix < n1);
    const int bi = in1 ? p : p2;
    const int bj = in1 ? p + ix : p2 + (ix - n1);
    const bool isdiag = in1 ? (ix == 0) : (ix == n1);

    if (bi != cur_bi) { cur_bi = bi; loadA(bi); }   // at most once per block

    // ---- MFMA tile: A in registers, B direct global->reg (L2-hot) ----
    f32x4 acc[2][4];
    #pragma unroll
    for (int fr = 0; fr < 2; ++fr)
      #pragma unroll
      for (int fc = 0; fc < 4; ++fc)
        acc[fr][fc] = (f32x4){0.f, 0.f, 0.f, 0.f};
    #pragma unroll
    for (int ks = 0; ks < 4; ++ks) {
      short8 bh[4];
      #pragma unroll
      for (int fc = 0; fc < 4; ++fc) {
        const int rb = bj * 128 + wx * 64 + fc * 16 + mcol;
        bh[fc] = *(const short8*)(xhi + (size_t)rb * DIMK + ks * 32 + q * 8);
      }
      #pragma unroll
      for (int fc = 0; fc < 4; ++fc) {
        acc[0][fc] = __builtin_amdgcn_mfma_f32_16x16x32_bf16(Ah[0][ks], bh[fc], acc[0][fc], 0, 0, 0);
        acc[1][fc] = __builtin_amdgcn_mfma_f32_16x16x32_bf16(Ah[1][ks], bh[fc], acc[1][fc], 0, 0, 0);
        acc[0][fc] = __builtin_amdgcn_mfma_f32_16x16x32_bf16(Al[0][ks], bh[fc], acc[0][fc], 0, 0, 0);
        acc[1][fc] = __builtin_amdgcn_mfma_f32_16x16x32_bf16(Al[1][ks], bh[fc], acc[1][fc], 0, 0, 0);
      }
    }

    // ---- all-negative epilogue (R10-proven). C: col=mcol, row=q*4+reg ----
    float cN[4] = {0.f, 0.f, 0.f, 0.f};
    if (!isdiag) {
      #pragma unroll
      for (int fr = 0; fr < 2; ++fr) {
        #pragma unroll
        for (int rg = 0; rg < 4; ++rg) {
          float vn = 0.f;
          #pragma unroll
          for (int fc = 0; fc < 4; ++fc) {
            const float s = acc[fr][fc][rg];
            const float t = fmaxf(fmaf(s, 8.f, -2.f), 0.f);
            const float e = __expf(t * t);   // exp(64*max(s-0.25,0)^2)
            vn += e; cN[fc] += e;
          }
          if (in1) rowNa[fr][rg] += vn; else rowNb[fr][rg] += vn;
        }
      }
    } else {
      #pragma unroll
      for (int fr = 0; fr < 2; ++fr) {
        #pragma unroll
        for (int rg = 0; rg < 4; ++rg) {
          const int rid = wy * 32 + fr * 16 + q * 4 + rg;
          float vn = 0.f;
          #pragma unroll
          for (int fc = 0; fc < 4; ++fc) {
            const int cid = wx * 64 + fc * 16 + mcol;
            const float s = acc[fr][fc][rg];
            const float t = fmaxf(fmaf(s, 8.f, -2.f), 0.f);
            float e = __expf(t * t);
            e = (rid == cid) ? 0.f : e;      // mask diagonal
            vn += e; cN[fc] += e;
          }
          if (in1) rowNa[fr][rg] += vn; else rowNb[fr][rg] += vn;
        }
      }
    }

    // col partials -> LDS (no global atomics in the loop)
    #pragma unroll
    for (int fc = 0; fc < 4; ++fc) {
      cN[fc] += __shfl_xor(cN[fc], 16);
      cN[fc] += __shfl_xor(cN[fc], 32);
    }
    if (q == 0) {
      #pragma unroll
      for (int fc = 0; fc < 4; ++fc)
        colbuf[tl][wy][wx * 64 + fc * 16 + mcol] = cN[fc];
    }
  }

  __syncthreads();   // all tiles done, colbuf complete

  // ---- end-of-block flushes: fire-and-forget device atomics ----
  for (int t = tid; t < ntile * 128; t += 512) {
    const int tl = t >> 7, col = t & 127;
    const int ix = t0 + tl;
    const bool in1 = (ix < n1);
    const bool dg = in1 ? (ix == 0) : (ix == n1);
    if (!dg) {
      const int bj = in1 ? p + ix : p2 + (ix - n1);
      const float sum = colbuf[tl][0][col] + colbuf[tl][1][col] +
                        colbuf[tl][2][col] + colbuf[tl][3][col];
      atomicAdd(&gN[bj * 128 + col], sum);
    }
  }
  #pragma unroll
  for (int set = 0; set < 2; ++set) {
    const int bi = set ? p2 : p;
    #pragma unroll
    for (int fr = 0; fr < 2; ++fr)
      #pragma unroll
      for (int rg = 0; rg < 4; ++rg) {
        float vn = set ? rowNb[fr][rg] : rowNa[fr][rg];
        #pragma unroll
        for (int m = 1; m < 16; m <<= 1) vn += __shfl_xor(vn, m);
        if (mcol == 0)
          atomicAdd(&gN[bi * 128 + wy * 32 + fr * 16 + q * 4 + rg], vn);
      }
  }

  // ---- fused sparse positive pass: this block = classes 2b, 2b+1 ----
  // 32 slots = 2 classes x 16 row-slots; 16 lanes per row (R11-proven math).
  {
    const int slot = tid >> 4;
    const int sl   = tid & 15;
    const int c = blockIdx.x * 2 + (slot & 1);
    const int m = min(cnt[c], CCAP);
    const int* cm = mem + c * CCAP;
    for (int i = (slot >> 1); i < m; i += 16) {
      const int a = cm[i];
      const int ablk = a >> 7;
      const short8 ha = *(const short8*)(xhi + (size_t)a * DIMK + sl * 8);
      const short8 la = *(const short8*)(xlo + (size_t)a * DIMK + sl * 8);
      float haf[8], af[8];
      #pragma unroll
      for (int k = 0; k < 8; ++k) {
        haf[k] = b2f((unsigned short)ha[k]);
        af[k]  = haf[k] + b2f((unsigned short)la[k]);
      }
      float sp = 0.f, sn = 0.f;
      for (int j = 0; j < m; ++j) {
        const int bb = cm[j];
        const bool aIsRow = (ablk <= (bb >> 7));  // dense orientation match
        const short8 hb = *(const short8*)(xhi + (size_t)bb * DIMK + sl * 8);
        float d = 0.f;
        if (aIsRow) {
          #pragma unroll
          for (int k = 0; k < 8; ++k)
            d = fmaf(af[k], b2f((unsigned short)hb[k]), d);
        } else {
          const short8 lb = *(const short8*)(xlo + (size_t)bb * DIMK + sl * 8);
          #pragma unroll
          for (int k = 0; k < 8; ++k)
            d = fmaf(haf[k],
                     b2f((unsigned short)hb[k]) + b2f((unsigned short)lb[k]), d);
        }
        #pragma unroll
        for (int sh = 1; sh < 16; sh <<= 1) d += __shfl_xor(d, sh);
        const float s = d;
        const float ap = fmaxf(1.25f - s, 0.f);
        sp += __expf(ap * fmaf(s, 64.f, -48.f));      // exp(-logit_p), incl diag
        const float t = fmaxf(fmaf(s, 8.f, -2.f), 0.f);
        sn += (a != bb) ? __expf(t * t) : 0.f;        // dense's wrongly-added e_n
      }
      if (sl == 0) {
        atomicAdd(&gP[a], sp);
        atomicAdd(&gN[a], -sn);
      }
    }
  }

  // ---- fence-free last-block finalize (R4-proven) ----
  __builtin_amdgcn_s_waitcnt(0);   // my atomics ack'd before counter bump
  __syncthreads();
  if (tid == 0) islast = (atomicAdd(counter, 1) == NBLKS - 1) ? 1 : 0;
  __syncthreads();
  if (islast) {
    float local = 0.f;
    #pragma unroll 1
    for (int bb = 0; bb < 2; ++bb) {
      const int base = bb * 4096 + tid * 8;
      float pv[8], nv[8];
      #pragma unroll
      for (int u = 0; u < 8; ++u) pv[u] = atomicAdd(&gP[base + u], 0.0f);
      #pragma unroll
      for (int u = 0; u < 8; ++u) nv[u] = atomicAdd(&gN[base + u], 0.0f);
      #pragma unroll
      for (int u = 0; u < 8; ++u) local += log1pf(pv[u] * nv[u]);
    }
    red[tid] = local;
    __syncthreads();
    for (int s2 = 256; s2 > 0; s2 >>= 1) {
      if (tid < s2) red[tid] += red[tid + s2];
      __syncthreads();
    }
    if (tid == 0) out[0] = red[0] / (float)NR;
  }
}

extern "C" void kernel_launch(void* const* d_in, const int* in_sizes, int n_in,
                              void* d_out, int out_size, void* d_ws, size_t ws_size,
                              hipStream_t stream) {
  const float* x  = (const float*)d_in[0];
  const int* tgt  = (const int*)d_in[1];
  float* out      = (float*)d_out;

  unsigned short* xhi = (unsigned short*)d_ws;
  unsigned short* xlo = xhi + (size_t)NR * DIMK;
  char* base = (char*)d_ws + (size_t)NR * DIMK * 4;   // 4MB
  float* gP = (float*)base;
  float* gN = gP + NR;
  int* counter = (int*)(gN + NR);
  int* cnt = counter + 16;            // 512 ints
  int* mem = cnt + 512;               // 512*CCAP ints

  hipMemsetAsync(cnt, 0, 512 * sizeof(int), stream);
  normalize_split_kernel<<<NR / 4, 256, 0, stream>>>(x, tgt, xhi, xlo, gP, gN,
                                                     counter, cnt, mem);
  simloss_kernel<<<NBLKS, 512, 0, stream>>>(xhi, xlo, cnt, mem, gP, gN, counter, out);
}